// Round 12
// baseline (110.252 us; speedup 1.0000x reference)
//
#include <hip/hip_runtime.h>
#include <hip/hip_bf16.h>

// FractalAttention on MI355X.
// Math: per level k, out = reshape-scatter( (x viewed [8192,1024]) @ Mcat_k + b ),
// where Mcat_k[j*128+d, h*128+e] = sum_d' W[k,h,d,d'] * w_mix[j*128+d', e].
// Mcat: one fused kernel reads fp32 W/wmix (concurrent staging, single
// barrier), builds bf16 hi/lo planes in LDS, 3-term MFMA (near-fp32), fp16.
// x -> fp16 via split_f16 (R11 profile: the fused fp32-A level-1 path was
// latency-bound at 42us; L3-hot fp16 input + gload_lds path runs ~20us).
// Levels: fp16 MFMA, 128x128 tile, BK=64, dbuf + counted vmcnt + XOR swizzle
// + setprio.

typedef __attribute__((ext_vector_type(8))) __bf16 bf16x8;
typedef __attribute__((ext_vector_type(8))) _Float16 half8;
typedef __attribute__((ext_vector_type(4))) float f32x4;
typedef __attribute__((ext_vector_type(4))) unsigned short us4;
typedef __attribute__((ext_vector_type(8))) unsigned short us8;

#define DEVI static __device__ __forceinline__

DEVI unsigned short f2bf(float f) {
  unsigned u = __builtin_bit_cast(unsigned, f);
  unsigned r = (u + 0x7fffu + ((u >> 16) & 1u)) >> 16;
  return (unsigned short)r;
}
DEVI float bf2f(unsigned short s) {
  return __builtin_bit_cast(float, (unsigned)s << 16);
}
DEVI unsigned short f2h(float f) {
  return __builtin_bit_cast(unsigned short, (_Float16)f);
}

DEVI void gload_lds16(const void* g, void* l) {
  __builtin_amdgcn_global_load_lds(
      (const __attribute__((address_space(1))) void*)g,
      (__attribute__((address_space(3))) void*)l,
      16, 0, 0);
}

// ---------------------------------------------------------------------------
// fp32 -> fp16 single plane (x input). 2048 blocks, float4 in / us4 out.
// ---------------------------------------------------------------------------
__global__ __launch_bounds__(256) void split_f16(
    const float* __restrict__ x, unsigned short* __restrict__ o, int n4)
{
  const int stride = gridDim.x * 256;
  for (int i = blockIdx.x * 256 + threadIdx.x; i < n4; i += stride) {
    const float4 v = ((const float4*)x)[i];
    us4 hv;
    hv[0] = f2h(v.x);
    hv[1] = f2h(v.y);
    hv[2] = f2h(v.z);
    hv[3] = f2h(v.w);
    ((us4*)o)[i] = hv;
  }
}

// ---------------------------------------------------------------------------
// Fused Mcat precompute. grid = (8 j, 32 lvlh), block = 256.
// Builds in LDS:  A[e][d2] = wmix[j*128+d2][e]  (bf16 hi/lo, [128][136] pad)
//                 B[d][d2] = W[lvlh][d][d2]     (bf16 hi/lo, [128][136] pad)
// Both staging passes issue before ONE barrier (concurrent MLP; wmix gather
// is L2-hot since each j-panel is reused by 32 lvlh-blocks).
// Then MT16[lvlh*131072 + e*1024 + j*128 + d] = 3-term MFMA(A,B), fp16.
// ---------------------------------------------------------------------------
__global__ __launch_bounds__(256, 1) void fused_prep(
    const float* __restrict__ W, const float* __restrict__ wmix,
    unsigned short* __restrict__ MT16)
{
  __shared__ unsigned short sAh[128 * 136];
  __shared__ unsigned short sAl[128 * 136];
  __shared__ unsigned short sBh[128 * 136];
  __shared__ unsigned short sBl[128 * 136];

  const int j = blockIdx.x;
  const int lvlh = blockIdx.y;
  const int tid = threadIdx.x;

  // B = W[lvlh] rows, coalesced-ish reads; thread: d = tid>>1, 64-col half.
  {
    const int d = tid >> 1, c0 = (tid & 1) * 64;
    const float* srcW = W + (size_t)lvlh * 16384 + (size_t)d * 128 + c0;
#pragma unroll
    for (int r8 = 0; r8 < 64; r8 += 8) {
      us8 hv, lv;
#pragma unroll
      for (int t = 0; t < 8; ++t) {
        const float m = srcW[r8 + t];
        const unsigned short hb = f2bf(m);
        hv[t] = hb;
        lv[t] = f2bf(m - bf2f(hb));
      }
      *(us8*)(sBh + d * 136 + c0 + r8) = hv;
      *(us8*)(sBl + d * 136 + c0 + r8) = lv;
    }
  }
  // A = wmix[j] transposed: scattered (512B-stride) fp32 reads, L2-hot.
  {
    const int e = tid >> 1, c0 = (tid & 1) * 64;
    const float* srcM = wmix + (size_t)(j * 128 + c0) * 128 + e;
#pragma unroll
    for (int r8 = 0; r8 < 64; r8 += 8) {
      us8 hv, lv;
#pragma unroll
      for (int t = 0; t < 8; ++t) {
        const float m = srcM[(size_t)(r8 + t) * 128];
        const unsigned short hb = f2bf(m);
        hv[t] = hb;
        lv[t] = f2bf(m - bf2f(hb));
      }
      *(us8*)(sAh + e * 136 + c0 + r8) = hv;
      *(us8*)(sAl + e * 136 + c0 + r8) = lv;
    }
  }
  __syncthreads();

  const int w = tid >> 6, lane = tid & 63;
  const int wm = w >> 1, wn = w & 1;
  const int l15 = lane & 15;
  f32x4 acc[4][4] = {};

#pragma unroll
  for (int kb = 0; kb < 2; ++kb) {
#pragma unroll
    for (int kk = 0; kk < 2; ++kk) {
      const int ko = kb * 64 + kk * 32 + ((lane >> 4) << 3);
      bf16x8 fah[4], fal[4], fbh[4], fbl[4];
#pragma unroll
      for (int m = 0; m < 4; ++m) {
        const int row = wm * 64 + m * 16 + l15;
        fah[m] = *(const bf16x8*)(sAh + row * 136 + ko);
        fal[m] = *(const bf16x8*)(sAl + row * 136 + ko);
      }
#pragma unroll
      for (int n = 0; n < 4; ++n) {
        const int col = wn * 64 + n * 16 + l15;
        fbh[n] = *(const bf16x8*)(sBh + col * 136 + ko);
        fbl[n] = *(const bf16x8*)(sBl + col * 136 + ko);
      }
#pragma unroll
      for (int m = 0; m < 4; ++m) {
#pragma unroll
        for (int n = 0; n < 4; ++n) {
          acc[m][n] = __builtin_amdgcn_mfma_f32_16x16x32_bf16(
              fah[m], fbh[n], acc[m][n], 0, 0, 0);
          acc[m][n] = __builtin_amdgcn_mfma_f32_16x16x32_bf16(
              fah[m], fbl[n], acc[m][n], 0, 0, 0);
          acc[m][n] = __builtin_amdgcn_mfma_f32_16x16x32_bf16(
              fal[m], fbh[n], acc[m][n], 0, 0, 0);
        }
      }
    }
  }

  const size_t mtbase = (size_t)lvlh * 131072 + (size_t)j * 128;
#pragma unroll
  for (int m = 0; m < 4; ++m) {
#pragma unroll
    for (int n = 0; n < 4; ++n) {
      const int d = wn * 64 + n * 16 + l15;
#pragma unroll
      for (int i = 0; i < 4; ++i) {
        const int e = wm * 64 + m * 16 + ((lane >> 4) << 2) + i;
        MT16[mtbase + (size_t)e * 1024 + d] = f2h(acc[m][n][i]);
      }
    }
  }
}

// ---------------------------------------------------------------------------
// Level GEMM (fp16): C[8192,1024] = A @ Mcat + bias, with the per-(coltile h)
// output row remap. 128x128 tile, BK=64, 4 waves (2x2), 16x16x32 f16 MFMA.
// Double-buffered LDS, counted vmcnt(8), XOR swizzle (both-sides involution),
// setprio around MFMA cluster.  OUT_MODE 0: fp16 plane; 1: fp32.
// grid = (64 rowtiles, 8 coltiles); id%8 XCD round-robin groups row%8.
// ---------------------------------------------------------------------------
template <int OUT_MODE>
__global__ __launch_bounds__(256, 2) void level_gemm_f16(
    const unsigned short* __restrict__ A16, const unsigned short* __restrict__ B,
    const float* __restrict__ bias, unsigned short* __restrict__ O16,
    float* __restrict__ Ofp, int lshift)
{
  __shared__ unsigned short sA[2][128 * 64];
  __shared__ unsigned short sB[2][128 * 64];

  const int tid = threadIdx.x;
  const int h = blockIdx.y;
  const int g0 = blockIdx.x * 128;

  const int w = tid >> 6, lane = tid & 63;
  const int srow = w * 8 + (lane >> 3);
  // swizzle involution: LDS slot lane&7 of row srow holds global 16B-slot
  // (lane&7)^(srow&7); srow&7 == lane>>3.
  const int xcol = ((lane & 7) ^ (lane >> 3)) * 8;
  const size_t aoff = (size_t)(g0 + srow) * 1024 + xcol;
  const size_t boff = (size_t)(h * 128 + srow) * 1024 + xcol;
  const int ldst = w * 512;

  f32x4 acc[4][4] = {};
  const int wm = w >> 1, wn = w & 1;
  const int l15 = lane & 15;

#define SFENCE() __builtin_amdgcn_sched_barrier(0)

#define STAGE_LG(buf, kc_)                                                  \
  {                                                                         \
    _Pragma("unroll") for (int i_ = 0; i_ < 4; ++i_) {                      \
      const size_t go_ = (size_t)i_ * 32 * 1024 + (size_t)(kc_);            \
      const int lo_ = ldst + i_ * 2048;                                     \
      gload_lds16(A16 + aoff + go_, sA[buf] + lo_);                         \
      gload_lds16(B + boff + go_, sB[buf] + lo_);                           \
    }                                                                       \
  }

  STAGE_LG(0, 0);
  int cur = 0;
#pragma unroll 1
  for (int kb = 0; kb < 16; ++kb) {
    if (kb < 15) {
      STAGE_LG(cur ^ 1, (kb + 1) * 64);
      asm volatile("s_waitcnt vmcnt(8)" ::: "memory");
    } else {
      asm volatile("s_waitcnt vmcnt(0)" ::: "memory");
    }
    SFENCE();
    __builtin_amdgcn_s_barrier();
    SFENCE();
    const unsigned short* sAc = sA[cur];
    const unsigned short* sBc = sB[cur];
#pragma unroll
    for (int kk = 0; kk < 2; ++kk) {
      half8 fa[4], fb[4];
      const int ko = (kk * 32 + ((lane >> 4) << 3)) ^ ((lane & 7) << 3);
#pragma unroll
      for (int m = 0; m < 4; ++m) {
        fa[m] = *(const half8*)(sAc + (wm * 64 + m * 16 + l15) * 64 + ko);
      }
#pragma unroll
      for (int n = 0; n < 4; ++n) {
        fb[n] = *(const half8*)(sBc + (wn * 64 + n * 16 + l15) * 64 + ko);
      }
      __builtin_amdgcn_s_setprio(1);
#pragma unroll
      for (int m = 0; m < 4; ++m) {
#pragma unroll
        for (int n = 0; n < 4; ++n) {
          acc[m][n] = __builtin_amdgcn_mfma_f32_16x16x32_f16(
              fa[m], fb[n], acc[m][n], 0, 0, 0);
        }
      }
      __builtin_amdgcn_s_setprio(0);
    }
    SFENCE();
    __builtin_amdgcn_s_barrier();
    SFENCE();
    cur ^= 1;
  }
#undef STAGE_LG
#undef SFENCE

  // Epilogue: out global row = b*8192 + n*L + h*(L/8) + r ; contiguous block.
  const int bss = lshift - 3;              // log2(L/8)
  const int q = g0 & 1023;
  const int n_idx = q >> bss;
  const int r0 = q & ((1 << bss) - 1);
  const long srow0 = (long)(g0 >> 10) * 8192 + ((long)n_idx << lshift) +
                     ((long)h << bss) + r0;
  const size_t obase = (size_t)srow0 * 128;

#pragma unroll
  for (int m = 0; m < 4; ++m) {
#pragma unroll
    for (int n = 0; n < 4; ++n) {
      const int col = wn * 64 + n * 16 + l15;
      const float bv = bias[col];
#pragma unroll
      for (int i = 0; i < 4; ++i) {
        const int row = wm * 64 + m * 16 + ((lane >> 4) << 2) + i;
        const float v = acc[m][n][i] + bv;
        const size_t p = obase + (size_t)row * 128 + col;
        if (OUT_MODE) {
          Ofp[p] = v;
        } else {
          O16[p] = f2h(v);
        }
      }
    }
  }
}

// ---------------------------------------------------------------------------
extern "C" void kernel_launch(void* const* d_in, const int* in_sizes, int n_in,
                              void* d_out, int out_size, void* d_ws,
                              size_t ws_size, hipStream_t stream) {
  const float* x = (const float*)d_in[0];
  const float* W = (const float*)d_in[1];    // [4,8,128,128]
  const float* wmx = (const float*)d_in[2];  // [1024,128]
  const float* bmx = (const float*)d_in[3];  // [128]
  float* out = (float*)d_out;

  const size_t NELEM = 8ull * 8192 * 128;  // 8388608
  const size_t MTSZ = 4ull * 1024 * 1024;  // 4194304 MT16 elems

  // ws layout (ushort elems): MT16 | Xa | Xc
  unsigned short* MT16 = (unsigned short*)d_ws;
  unsigned short* Xa = MT16 + MTSZ;  // 16 MB
  unsigned short* Xc = Xa + NELEM;   // 16 MB
  // d_out lower half doubles as the level-1 output plane
  unsigned short* Xb = (unsigned short*)d_out;

  fused_prep<<<dim3(8, 32), dim3(256), 0, stream>>>(W, wmx, MT16);
  split_f16<<<dim3(2048), dim3(256), 0, stream>>>(x, Xa, (int)(NELEM / 4));

  dim3 grid(64, 8), blk(256);
  // Level 1 (L=1024): Xa -> Xb (d_out lower half)
  level_gemm_f16<0><<<grid, blk, 0, stream>>>(
      Xa, MT16 + 0 * 1048576ull, bmx, Xb, nullptr, 10);
  // Level 2 (L=2048): Xb -> Xc
  level_gemm_f16<0><<<grid, blk, 0, stream>>>(
      Xb, MT16 + 1 * 1048576ull, bmx, Xc, nullptr, 11);
  // Level 3 (L=4096): Xc -> Xa
  level_gemm_f16<0><<<grid, blk, 0, stream>>>(
      Xc, MT16 + 2 * 1048576ull, bmx, Xa, nullptr, 12);
  // Level 4 (L=8192): Xa -> fp32 out (full d_out overwrite)
  level_gemm_f16<1><<<grid, blk, 0, stream>>>(
      Xa, MT16 + 3 * 1048576ull, bmx, nullptr, out, 13);
}

// Round 13
// 106.794 us; speedup vs baseline: 1.0324x; 1.0324x over previous
//
#include <hip/hip_runtime.h>
#include <hip/hip_bf16.h>

// FractalAttention on MI355X.
// Math: per level k, out = reshape-scatter( (x viewed [8192,1024]) @ Mcat_k + b ),
// where Mcat_k[j*128+d, h*128+e] = sum_d' W[k,h,d,d'] * w_mix[j*128+d', e].
// Mcat: one fused kernel reads fp32 W/wmix (concurrent staging, single
// barrier), builds bf16 hi/lo planes in LDS, 3-term MFMA (near-fp32), fp16.
// Levels: fp16 MFMA, 128x128 tile, BK=64, dbuf + counted vmcnt + XOR swizzle
// + setprio. Level 1 reads x fp32 directly with a 2-deep A-register pipeline
// and FIFO-counted vmcnt (R11 profile: the 1-deep drain-vmcnt(0) variant was
// latency-bound at 42us, MfmaUtil 15%).

typedef __attribute__((ext_vector_type(8))) __bf16 bf16x8;
typedef __attribute__((ext_vector_type(8))) _Float16 half8;
typedef __attribute__((ext_vector_type(4))) float f32x4;
typedef __attribute__((ext_vector_type(8))) unsigned short us8;

#define DEVI static __device__ __forceinline__

DEVI unsigned short f2bf(float f) {
  unsigned u = __builtin_bit_cast(unsigned, f);
  unsigned r = (u + 0x7fffu + ((u >> 16) & 1u)) >> 16;
  return (unsigned short)r;
}
DEVI float bf2f(unsigned short s) {
  return __builtin_bit_cast(float, (unsigned)s << 16);
}
DEVI unsigned short f2h(float f) {
  return __builtin_bit_cast(unsigned short, (_Float16)f);
}

DEVI void gload_lds16(const void* g, void* l) {
  __builtin_amdgcn_global_load_lds(
      (const __attribute__((address_space(1))) void*)g,
      (__attribute__((address_space(3))) void*)l,
      16, 0, 0);
}

// ---------------------------------------------------------------------------
// Fused Mcat precompute. grid = (8 j, 32 lvlh), block = 256.
// Builds in LDS:  A[e][d2] = wmix[j*128+d2][e]  (bf16 hi/lo, [128][136] pad)
//                 B[d][d2] = W[lvlh][d][d2]     (bf16 hi/lo, [128][136] pad)
// Both staging passes issue before ONE barrier (concurrent MLP; wmix gather
// is L2-hot since each j-panel is reused by 32 lvlh-blocks).
// Then MT16[lvlh*131072 + e*1024 + j*128 + d] = 3-term MFMA(A,B), fp16.
// ---------------------------------------------------------------------------
__global__ __launch_bounds__(256, 1) void fused_prep(
    const float* __restrict__ W, const float* __restrict__ wmix,
    unsigned short* __restrict__ MT16)
{
  __shared__ unsigned short sAh[128 * 136];
  __shared__ unsigned short sAl[128 * 136];
  __shared__ unsigned short sBh[128 * 136];
  __shared__ unsigned short sBl[128 * 136];

  const int j = blockIdx.x;
  const int lvlh = blockIdx.y;
  const int tid = threadIdx.x;

  // B = W[lvlh] rows, coalesced-ish reads; thread: d = tid>>1, 64-col half.
  {
    const int d = tid >> 1, c0 = (tid & 1) * 64;
    const float* srcW = W + (size_t)lvlh * 16384 + (size_t)d * 128 + c0;
#pragma unroll
    for (int r8 = 0; r8 < 64; r8 += 8) {
      us8 hv, lv;
#pragma unroll
      for (int t = 0; t < 8; ++t) {
        const float m = srcW[r8 + t];
        const unsigned short hb = f2bf(m);
        hv[t] = hb;
        lv[t] = f2bf(m - bf2f(hb));
      }
      *(us8*)(sBh + d * 136 + c0 + r8) = hv;
      *(us8*)(sBl + d * 136 + c0 + r8) = lv;
    }
  }
  // A = wmix[j] transposed: scattered (512B-stride) fp32 reads, L2-hot.
  {
    const int e = tid >> 1, c0 = (tid & 1) * 64;
    const float* srcM = wmix + (size_t)(j * 128 + c0) * 128 + e;
#pragma unroll
    for (int r8 = 0; r8 < 64; r8 += 8) {
      us8 hv, lv;
#pragma unroll
      for (int t = 0; t < 8; ++t) {
        const float m = srcM[(size_t)(r8 + t) * 128];
        const unsigned short hb = f2bf(m);
        hv[t] = hb;
        lv[t] = f2bf(m - bf2f(hb));
      }
      *(us8*)(sAh + e * 136 + c0 + r8) = hv;
      *(us8*)(sAl + e * 136 + c0 + r8) = lv;
    }
  }
  __syncthreads();

  const int w = tid >> 6, lane = tid & 63;
  const int wm = w >> 1, wn = w & 1;
  const int l15 = lane & 15;
  f32x4 acc[4][4] = {};

#pragma unroll
  for (int kb = 0; kb < 2; ++kb) {
#pragma unroll
    for (int kk = 0; kk < 2; ++kk) {
      const int ko = kb * 64 + kk * 32 + ((lane >> 4) << 3);
      bf16x8 fah[4], fal[4], fbh[4], fbl[4];
#pragma unroll
      for (int m = 0; m < 4; ++m) {
        const int row = wm * 64 + m * 16 + l15;
        fah[m] = *(const bf16x8*)(sAh + row * 136 + ko);
        fal[m] = *(const bf16x8*)(sAl + row * 136 + ko);
      }
#pragma unroll
      for (int n = 0; n < 4; ++n) {
        const int col = wn * 64 + n * 16 + l15;
        fbh[n] = *(const bf16x8*)(sBh + col * 136 + ko);
        fbl[n] = *(const bf16x8*)(sBl + col * 136 + ko);
      }
#pragma unroll
      for (int m = 0; m < 4; ++m) {
#pragma unroll
        for (int n = 0; n < 4; ++n) {
          acc[m][n] = __builtin_amdgcn_mfma_f32_16x16x32_bf16(
              fah[m], fbh[n], acc[m][n], 0, 0, 0);
          acc[m][n] = __builtin_amdgcn_mfma_f32_16x16x32_bf16(
              fah[m], fbl[n], acc[m][n], 0, 0, 0);
          acc[m][n] = __builtin_amdgcn_mfma_f32_16x16x32_bf16(
              fal[m], fbh[n], acc[m][n], 0, 0, 0);
        }
      }
    }
  }

  const size_t mtbase = (size_t)lvlh * 131072 + (size_t)j * 128;
#pragma unroll
  for (int m = 0; m < 4; ++m) {
#pragma unroll
    for (int n = 0; n < 4; ++n) {
      const int d = wn * 64 + n * 16 + l15;
#pragma unroll
      for (int i = 0; i < 4; ++i) {
        const int e = wm * 64 + m * 16 + ((lane >> 4) << 2) + i;
        MT16[mtbase + (size_t)e * 1024 + d] = f2h(acc[m][n][i]);
      }
    }
  }
}

// ---------------------------------------------------------------------------
// Level GEMM (fp16): C[8192,1024] = A @ Mcat + bias, with the per-(coltile h)
// output row remap. 128x128 tile, BK=64, 4 waves (2x2), 16x16x32 f16 MFMA.
// Double-buffered LDS, counted vmcnt, XOR swizzle (both-sides involution),
// setprio around MFMA cluster.
// IN_MODE 0: A fp16 via gload_lds (counted vmcnt(8)).
// IN_MODE 1: A fp32, 2-deep reg-staged convert (sets alternate with tile
//   parity; FIFO-counted vmcnt(12)/vmcnt(8) keeps next A-tile in flight).
// OUT_MODE 0: fp16 plane; 1: fp32.
// grid = (64 rowtiles, 8 coltiles); id%8 XCD round-robin groups row%8.
// ---------------------------------------------------------------------------
template <int IN_MODE, int OUT_MODE>
__global__ __launch_bounds__(256, 2) void level_gemm_f16(
    const float* __restrict__ A32, const unsigned short* __restrict__ A16,
    const unsigned short* __restrict__ B, const float* __restrict__ bias,
    unsigned short* __restrict__ O16, float* __restrict__ Ofp, int lshift)
{
  __shared__ unsigned short sA[2][128 * 64];
  __shared__ unsigned short sB[2][128 * 64];

  const int tid = threadIdx.x;
  const int h = blockIdx.y;
  const int g0 = blockIdx.x * 128;

  const int w = tid >> 6, lane = tid & 63;
  const int srow = w * 8 + (lane >> 3);
  // swizzle involution: LDS slot lane&7 of row srow holds global 16B-slot
  // (lane&7)^(srow&7); srow&7 == lane>>3.
  const int xcol = ((lane & 7) ^ (lane >> 3)) * 8;
  const size_t aoff = (size_t)(g0 + srow) * 1024 + xcol;
  const size_t boff = (size_t)(h * 128 + srow) * 1024 + xcol;
  const int ldst = w * 512;

  f32x4 acc[4][4] = {};
  const int wm = w >> 1, wn = w & 1;
  const int l15 = lane & 15;

#define COMPUTE_TILE(sAc, sBc)                                              \
  {                                                                         \
    _Pragma("unroll") for (int kk = 0; kk < 2; ++kk) {                      \
      half8 fa[4], fb[4];                                                   \
      const int ko = (kk * 32 + ((lane >> 4) << 3)) ^ ((lane & 7) << 3);    \
      _Pragma("unroll") for (int m = 0; m < 4; ++m) {                       \
        fa[m] = *(const half8*)((sAc) + (wm * 64 + m * 16 + l15) * 64 + ko);\
      }                                                                     \
      _Pragma("unroll") for (int n = 0; n < 4; ++n) {                       \
        fb[n] = *(const half8*)((sBc) + (wn * 64 + n * 16 + l15) * 64 + ko);\
      }                                                                     \
      __builtin_amdgcn_s_setprio(1);                                        \
      _Pragma("unroll") for (int m = 0; m < 4; ++m) {                       \
        _Pragma("unroll") for (int n = 0; n < 4; ++n) {                     \
          acc[m][n] = __builtin_amdgcn_mfma_f32_16x16x32_f16(               \
              fa[m], fb[n], acc[m][n], 0, 0, 0);                            \
        }                                                                   \
      }                                                                     \
      __builtin_amdgcn_s_setprio(0);                                        \
    }                                                                       \
  }

#define SFENCE() __builtin_amdgcn_sched_barrier(0)

  if constexpr (IN_MODE == 0) {
    // ---- proven path: both A and B via gload_lds, counted vmcnt(8) ----
#define STAGE_LG(buf, kc_)                                                  \
    {                                                                       \
      _Pragma("unroll") for (int i_ = 0; i_ < 4; ++i_) {                    \
        const size_t go_ = (size_t)i_ * 32 * 1024 + (size_t)(kc_);          \
        const int lo_ = ldst + i_ * 2048;                                   \
        gload_lds16(A16 + aoff + go_, sA[buf] + lo_);                       \
        gload_lds16(B + boff + go_, sB[buf] + lo_);                         \
      }                                                                     \
    }
    STAGE_LG(0, 0);
    int cur = 0;
#pragma unroll 1
    for (int kb = 0; kb < 16; ++kb) {
      if (kb < 15) {
        STAGE_LG(cur ^ 1, (kb + 1) * 64);
        asm volatile("s_waitcnt vmcnt(8)" ::: "memory");
      } else {
        asm volatile("s_waitcnt vmcnt(0)" ::: "memory");
      }
      SFENCE();
      __builtin_amdgcn_s_barrier();
      SFENCE();
      COMPUTE_TILE(sA[cur], sB[cur]);
      SFENCE();
      __builtin_amdgcn_s_barrier();
      SFENCE();
      cur ^= 1;
    }
#undef STAGE_LG
  } else {
    // ---- fp32-A path, 2-deep A-reg pipeline, FIFO-counted waits ----
    // VM issue order (per thread): A(t) = 8 global_load_dwordx4,
    // B(t) = 4 global_load_lds. Steady state outstanding at iter kb top:
    // [A(kb) 8 | B(kb) 4 | A(kb+1) 8] -> vmcnt(12) completes A(kb),
    // vmcnt(8) completes B(kb) while A(kb+1) stays in flight.
    float4 e0[4], e1[4];  // set for even tiles
    float4 o0[4], o1[4];  // set for odd tiles
#define ISS_A(S0, S1, kc_)                                                  \
    {                                                                       \
      _Pragma("unroll") for (int i_ = 0; i_ < 4; ++i_) {                    \
        const float* p_ = A32 + aoff + (size_t)i_ * 32768 + (size_t)(kc_);  \
        S0[i_] = *(const float4*)p_;                                        \
        S1[i_] = *(const float4*)(p_ + 4);                                  \
      }                                                                     \
    }
#define WR_A(S0, S1, buf)                                                   \
    {                                                                       \
      _Pragma("unroll") for (int i_ = 0; i_ < 4; ++i_) {                    \
        us8 hv_;                                                            \
        hv_[0] = f2h(S0[i_].x); hv_[1] = f2h(S0[i_].y);                     \
        hv_[2] = f2h(S0[i_].z); hv_[3] = f2h(S0[i_].w);                     \
        hv_[4] = f2h(S1[i_].x); hv_[5] = f2h(S1[i_].y);                     \
        hv_[6] = f2h(S1[i_].z); hv_[7] = f2h(S1[i_].w);                     \
        *(us8*)(sA[buf] + ldst + i_ * 2048 + lane * 8) = hv_;               \
      }                                                                     \
    }
#define STG_B(buf, kc_)                                                     \
    {                                                                       \
      _Pragma("unroll") for (int i_ = 0; i_ < 4; ++i_) {                    \
        gload_lds16(B + boff + (size_t)i_ * 32768 + (size_t)(kc_),          \
                    sB[buf] + ldst + i_ * 2048);                            \
      }                                                                     \
    }
    ISS_A(e0, e1, 0);        // A tile 0
    STG_B(0, 0);             // B tile 0
    ISS_A(o0, o1, 64);       // A tile 1

#pragma unroll 1
    for (int kb2 = 0; kb2 < 16; kb2 += 2) {
      // ===== even tile kb = kb2 (cur = 0, set e) =====
      asm volatile("s_waitcnt vmcnt(12)" ::: "memory");   // A(kb) done
      SFENCE();
      WR_A(e0, e1, 0);
      asm volatile("s_waitcnt vmcnt(8) lgkmcnt(0)" ::: "memory");  // B(kb)
      SFENCE();
      __builtin_amdgcn_s_barrier();
      SFENCE();
      STG_B(1, (kb2 + 1) * 64);                 // B(kb+1), always exists
      if (kb2 < 14) ISS_A(e0, e1, (kb2 + 2) * 64);  // A(kb+2)
      SFENCE();
      COMPUTE_TILE(sA[0], sB[0]);
      SFENCE();
      __builtin_amdgcn_s_barrier();
      SFENCE();

      // ===== odd tile kb = kb2+1 (cur = 1, set o) =====
      if (kb2 < 14) {
        asm volatile("s_waitcnt vmcnt(12)" ::: "memory");  // A(kb) done
      } else {
        asm volatile("s_waitcnt vmcnt(4)" ::: "memory");   // tail: only B left
      }
      SFENCE();
      WR_A(o0, o1, 1);
      if (kb2 < 14) {
        asm volatile("s_waitcnt vmcnt(8) lgkmcnt(0)" ::: "memory");
      } else {
        asm volatile("s_waitcnt vmcnt(0) lgkmcnt(0)" ::: "memory");
      }
      SFENCE();
      __builtin_amdgcn_s_barrier();
      SFENCE();
      if (kb2 < 14) STG_B(0, (kb2 + 2) * 64);       // B(kb+2)
      if (kb2 < 13) ISS_A(o0, o1, (kb2 + 3) * 64);  // A(kb+3)
      SFENCE();
      COMPUTE_TILE(sA[1], sB[1]);
      SFENCE();
      __builtin_amdgcn_s_barrier();
      SFENCE();
    }
#undef ISS_A
#undef WR_A
#undef STG_B
  }
#undef COMPUTE_TILE
#undef SFENCE

  // Epilogue: out global row = b*8192 + n*L + h*(L/8) + r ; contiguous block.
  const int bss = lshift - 3;              // log2(L/8)
  const int q = g0 & 1023;
  const int n_idx = q >> bss;
  const int r0 = q & ((1 << bss) - 1);
  const long srow0 = (long)(g0 >> 10) * 8192 + ((long)n_idx << lshift) +
                     ((long)h << bss) + r0;
  const size_t obase = (size_t)srow0 * 128;

#pragma unroll
  for (int m = 0; m < 4; ++m) {
#pragma unroll
    for (int n = 0; n < 4; ++n) {
      const int col = wn * 64 + n * 16 + l15;
      const float bv = bias[col];
#pragma unroll
      for (int i = 0; i < 4; ++i) {
        const int row = wm * 64 + m * 16 + ((lane >> 4) << 2) + i;
        const float v = acc[m][n][i] + bv;
        const size_t p = obase + (size_t)row * 128 + col;
        if (OUT_MODE) {
          Ofp[p] = v;
        } else {
          O16[p] = f2h(v);
        }
      }
    }
  }
}

// ---------------------------------------------------------------------------
extern "C" void kernel_launch(void* const* d_in, const int* in_sizes, int n_in,
                              void* d_out, int out_size, void* d_ws,
                              size_t ws_size, hipStream_t stream) {
  const float* x = (const float*)d_in[0];
  const float* W = (const float*)d_in[1];    // [4,8,128,128]
  const float* wmx = (const float*)d_in[2];  // [1024,128]
  const float* bmx = (const float*)d_in[3];  // [128]
  float* out = (float*)d_out;

  const size_t NELEM = 8ull * 8192 * 128;  // 8388608
  const size_t MTSZ = 4ull * 1024 * 1024;  // 4194304 MT16 elems

  // ws layout (ushort elems): MT16 | Xa | Xc
  unsigned short* MT16 = (unsigned short*)d_ws;
  unsigned short* Xa = MT16 + MTSZ;  // 16 MB
  unsigned short* Xc = Xa + NELEM;   // 16 MB
  // d_out lower half doubles as the level-1 output plane
  unsigned short* Xb = (unsigned short*)d_out;

  fused_prep<<<dim3(8, 32), dim3(256), 0, stream>>>(W, wmx, MT16);

  dim3 grid(64, 8), blk(256);
  // Level 1 (L=1024): x (fp32) -> Xb (d_out lower half)
  level_gemm_f16<1, 0><<<grid, blk, 0, stream>>>(
      x, nullptr, MT16 + 0 * 1048576ull, bmx, Xb, nullptr, 10);
  // Level 2 (L=2048): Xb -> Xc
  level_gemm_f16<0, 0><<<grid, blk, 0, stream>>>(
      nullptr, Xb, MT16 + 1 * 1048576ull, bmx, Xc, nullptr, 11);
  // Level 3 (L=4096): Xc -> Xa
  level_gemm_f16<0, 0><<<grid, blk, 0, stream>>>(
      nullptr, Xc, MT16 + 2 * 1048576ull, bmx, Xa, nullptr, 12);
  // Level 4 (L=8192): Xa -> fp32 out (full d_out overwrite)
  level_gemm_f16<0, 1><<<grid, blk, 0, stream>>>(
      nullptr, Xa, MT16 + 3 * 1048576ull, bmx, nullptr, out, 13);
}